// Round 2
// baseline (1104.884 us; speedup 1.0000x reference)
//
#include <hip/hip_runtime.h>

// Problem constants (from reference): N=512, OBS=32, H=128, M=128, L=3
#define NA 512
#define NOBS 32
#define NH 128

typedef const float* fp32p;

// ---------------------------------------------------------------- dist ------
__global__ __launch_bounds__(256) void dist_kernel(fp32p pos, float* __restrict__ dist) {
    const int i = blockIdx.x;
    const float xi = pos[2 * i];
    const float yi = pos[2 * i + 1];
    for (int j = threadIdx.x; j < NA; j += 256) {
        float dx = xi - pos[2 * j];
        float dy = yi - pos[2 * j + 1];
        float s = dx * dx + dy * dy;
        dist[i * NA + j] = (i == j) ? 0.0f : sqrtf(s);
    }
}

// ------------------------------------------------------------- encoder ------
__global__ __launch_bounds__(128) void encoder_kernel(
    fp32p obs, fp32p W1, fp32p b1, fp32p W2, fp32p b2, fp32p W3, fp32p b3,
    float* __restrict__ z) {
    __shared__ float xs[NOBS];
    __shared__ float h1s[NH];
    __shared__ float h2s[NH];
    const int i = blockIdx.x, t = threadIdx.x;
    if (t < NOBS) xs[t] = obs[i * NOBS + t];
    __syncthreads();
    float a = b1[t];
    for (int k = 0; k < NOBS; ++k) a += xs[k] * W1[t * NOBS + k];
    h1s[t] = fmaxf(a, 0.0f);
    __syncthreads();
    a = b2[t];
    for (int k = 0; k < NH; ++k) a += h1s[k] * W2[t * NH + k];
    h2s[t] = fmaxf(a, 0.0f);
    __syncthreads();
    a = b3[t];
    for (int k = 0; k < NH; ++k) a += h2s[k] * W3[t * NH + k];
    z[i * NH + t] = a;
}

// ------------------------------------------------- A = z@Wi.T, B = z@Wj.T ---
__global__ __launch_bounds__(128) void ab_kernel(
    const float* __restrict__ z, fp32p W1l, float* __restrict__ A, float* __restrict__ B) {
    __shared__ float zs[NH];
    const int i = blockIdx.x, m = threadIdx.x;
    zs[m] = z[i * NH + m];
    __syncthreads();
    const float* wr = W1l + m * 257;
    float a = 0.0f, b = 0.0f;
    for (int k = 0; k < NH; ++k) {
        float zk = zs[k];
        a += zk * wr[k];
        b += zk * wr[NH + k];
    }
    A[i * NH + m] = a;
    B[i * NH + m] = b;
}

// ------------------------------------------------------- fused message ------
// One block per target agent i. For j-chunks of 64 rows:
//   h1 = relu(A_i + B_j + dist_ij*wd + b1)   (64x128, LDS)
//   h2 = relu(h1 @ W2.T + b2)                (64x128, LDS)
//   m  = h2 @ W3.T + b3 ; msum_i += sum_{j != i} m_j
// W2/W3 staged into one LDS buffer per phase (stride 130 kills the
// 32-way bank conflict on the row-stride-128 weight reads; residual
// 2-way is free per m136).  Static LDS ~138 KB: compiled fine on gfx950
// in round 1 -> per-workgroup limit is the 160 KB CDNA4 LDS.
#define WSTR 130
__global__ __launch_bounds__(512) void msg_kernel(
    const float* __restrict__ A, const float* __restrict__ B,
    const float* __restrict__ dist,
    fp32p W1l, fp32p b1, fp32p W2, fp32p b2, fp32p W3, fp32p b3,
    float* __restrict__ msum) {
    const int i = blockIdx.x;
    const int t = threadIdx.x;
    __shared__ float Ws[NH * WSTR];       // 66560 B
    __shared__ float h1s[64 * WSTR];      // 33280 B
    __shared__ float h2s[64 * WSTR];      // 33280 B
    __shared__ float Arow[NH], wds[NH], b1s[NH], b2s[NH], b3s[NH];
    __shared__ float distrow[NA];
    __shared__ float msum_s[NH];

    if (t < NH) {
        Arow[t] = A[i * NH + t];
        wds[t]  = W1l[t * 257 + 256];
        b1s[t]  = b1[t];
        b2s[t]  = b2[t];
        b3s[t]  = b3[t];
        msum_s[t] = 0.0f;
    }
    for (int j = t; j < NA; j += 512) distrow[j] = dist[i * NA + j];

    const int tx = t & 31;    // n = tx + 32*ii
    const int ty = t >> 5;    // 0..15 ; j = ty*4 + jj
    float psum[4] = {0.f, 0.f, 0.f, 0.f};

    for (int c = 0; c < 8; ++c) {
        const int j0 = c * 64;
        __syncthreads();  // prev GEMM2 done reading h2s/Ws before overwrite

        // build h1 chunk (each thread: one column m, 16 rows)
        {
            const int m  = t & 127;
            const int r0 = t >> 7;   // 0..3
            const float am  = Arow[m] + b1s[m];
            const float wdm = wds[m];
            #pragma unroll
            for (int p = 0; p < 16; ++p) {
                const int j = r0 + p * 4;
                float v = am + B[(j0 + j) * NH + m] + distrow[j0 + j] * wdm;
                h1s[j * WSTR + m] = fmaxf(v, 0.0f);
            }
        }
        // stage W2
        for (int e = t; e < NH * NH; e += 512)
            Ws[(e >> 7) * WSTR + (e & 127)] = W2[e];
        __syncthreads();

        // GEMM1: acc[jj][ii] = sum_k h1[ty*4+jj][k] * W2[tx+32*ii][k]
        float acc[4][4];
        #pragma unroll
        for (int jj = 0; jj < 4; ++jj)
            #pragma unroll
            for (int ii = 0; ii < 4; ++ii) acc[jj][ii] = 0.0f;
        #pragma unroll 4
        for (int k = 0; k < NH; ++k) {
            float h[4], w[4];
            #pragma unroll
            for (int jj = 0; jj < 4; ++jj) h[jj] = h1s[(ty * 4 + jj) * WSTR + k];
            #pragma unroll
            for (int ii = 0; ii < 4; ++ii) w[ii] = Ws[(tx + 32 * ii) * WSTR + k];
            #pragma unroll
            for (int jj = 0; jj < 4; ++jj)
                #pragma unroll
                for (int ii = 0; ii < 4; ++ii) acc[jj][ii] += h[jj] * w[ii];
        }
        __syncthreads();  // everyone done reading Ws/h1s before overwrite

        // write h2 (+b2, relu) and stage W3
        #pragma unroll
        for (int jj = 0; jj < 4; ++jj)
            #pragma unroll
            for (int ii = 0; ii < 4; ++ii)
                h2s[(ty * 4 + jj) * WSTR + (tx + 32 * ii)] =
                    fmaxf(acc[jj][ii] + b2s[tx + 32 * ii], 0.0f);
        for (int e = t; e < NH * NH; e += 512)
            Ws[(e >> 7) * WSTR + (e & 127)] = W3[e];
        __syncthreads();

        // GEMM2 + diag-masked column-sum accumulation
        #pragma unroll
        for (int jj = 0; jj < 4; ++jj)
            #pragma unroll
            for (int ii = 0; ii < 4; ++ii) acc[jj][ii] = 0.0f;
        #pragma unroll 4
        for (int k = 0; k < NH; ++k) {
            float h[4], w[4];
            #pragma unroll
            for (int jj = 0; jj < 4; ++jj) h[jj] = h2s[(ty * 4 + jj) * WSTR + k];
            #pragma unroll
            for (int ii = 0; ii < 4; ++ii) w[ii] = Ws[(tx + 32 * ii) * WSTR + k];
            #pragma unroll
            for (int jj = 0; jj < 4; ++jj)
                #pragma unroll
                for (int ii = 0; ii < 4; ++ii) acc[jj][ii] += h[jj] * w[ii];
        }
        #pragma unroll
        for (int jj = 0; jj < 4; ++jj) {
            const int jg = j0 + ty * 4 + jj;
            if (jg != i) {
                #pragma unroll
                for (int ii = 0; ii < 4; ++ii)
                    psum[ii] += acc[jj][ii] + b3s[tx + 32 * ii];
            }
        }
    }
    __syncthreads();
    #pragma unroll
    for (int ii = 0; ii < 4; ++ii) atomicAdd(&msum_s[tx + 32 * ii], psum[ii]);
    __syncthreads();
    if (t < NH) msum[i * NH + t] = msum_s[t];
}

// -------------------------------------------------------------- update ------
__global__ __launch_bounds__(128) void upd_kernel(
    const float* __restrict__ z, const float* __restrict__ msum,
    fp32p W1, fp32p b1, fp32p W2, fp32p b2, fp32p W3, fp32p b3,
    float* __restrict__ zout) {
    __shared__ float xs[2 * NH];
    __shared__ float h1s[NH];
    __shared__ float h2s[NH];
    const int i = blockIdx.x, t = threadIdx.x;
    xs[t]      = z[i * NH + t];
    xs[NH + t] = msum[i * NH + t];
    __syncthreads();
    float a = b1[t];
    for (int k = 0; k < 2 * NH; ++k) a += xs[k] * W1[t * 2 * NH + k];
    h1s[t] = fmaxf(a, 0.0f);
    __syncthreads();
    a = b2[t];
    for (int k = 0; k < NH; ++k) a += h1s[k] * W2[t * NH + k];
    h2s[t] = fmaxf(a, 0.0f);
    __syncthreads();
    a = b3[t];
    for (int k = 0; k < NH; ++k) a += h2s[k] * W3[t * NH + k];
    zout[i * NH + t] = a;
}

// ---------------------------------------------------------------- host ------
extern "C" void kernel_launch(void* const* d_in, const int* in_sizes, int n_in,
                              void* d_out, int out_size, void* d_ws, size_t ws_size,
                              hipStream_t stream) {
    fp32p obs   = (fp32p)d_in[0];
    fp32p pos   = (fp32p)d_in[1];
    fp32p encW1 = (fp32p)d_in[2];  fp32p encb1 = (fp32p)d_in[3];
    fp32p encW2 = (fp32p)d_in[4];  fp32p encb2 = (fp32p)d_in[5];
    fp32p encW3 = (fp32p)d_in[6];  fp32p encb3 = (fp32p)d_in[7];
    fp32p msgW1 = (fp32p)d_in[8];  fp32p msgb1 = (fp32p)d_in[9];
    fp32p msgW2 = (fp32p)d_in[10]; fp32p msgb2 = (fp32p)d_in[11];
    fp32p msgW3 = (fp32p)d_in[12]; fp32p msgb3 = (fp32p)d_in[13];
    fp32p updW1 = (fp32p)d_in[14]; fp32p updb1 = (fp32p)d_in[15];
    fp32p updW2 = (fp32p)d_in[16]; fp32p updb2 = (fp32p)d_in[17];
    fp32p updW3 = (fp32p)d_in[18]; fp32p updb3 = (fp32p)d_in[19];

    // workspace layout (fp32): dist 512x512 | zA | zB | A | B | msum  (~2.36 MB)
    float* ws   = (float*)d_ws;
    float* dist = ws;
    float* zA   = dist + NA * NA;
    float* zB   = zA + NA * NH;
    float* Ab   = zB + NA * NH;
    float* Bb   = Ab + NA * NH;
    float* ms   = Bb + NA * NH;

    dist_kernel<<<NA, 256, 0, stream>>>(pos, dist);
    encoder_kernel<<<NA, 128, 0, stream>>>(obs, encW1, encb1, encW2, encb2, encW3, encb3, zA);

    float* zin = zA;
    float* zout = zB;
    for (int l = 0; l < 3; ++l) {
        ab_kernel<<<NA, 128, 0, stream>>>(zin, msgW1 + (size_t)l * 128 * 257, Ab, Bb);
        msg_kernel<<<NA, 512, 0, stream>>>(Ab, Bb, dist,
            msgW1 + (size_t)l * 128 * 257, msgb1 + l * 128,
            msgW2 + (size_t)l * 128 * 128, msgb2 + l * 128,
            msgW3 + (size_t)l * 128 * 128, msgb3 + l * 128, ms);
        float* dst = (l == 2) ? (float*)d_out : zout;
        upd_kernel<<<NA, 128, 0, stream>>>(zin, ms,
            updW1 + (size_t)l * 256 * 128, updb1 + l * 128,
            updW2 + (size_t)l * 128 * 128, updb2 + l * 128,
            updW3 + (size_t)l * 128 * 128, updb3 + l * 128, dst);
        float* tmp = zin; zin = zout; zout = tmp;
    }
}

// Round 3
// 290.818 us; speedup vs baseline: 3.7992x; 3.7992x over previous
//
#include <hip/hip_runtime.h>

// Problem constants (from reference): N=512, OBS=32, H=128, M=128, L=3
#define NA 512
#define NOBS 32
#define NH 128

typedef const float* fp32p;
typedef __attribute__((ext_vector_type(8))) short bf16x8;
typedef __attribute__((ext_vector_type(4))) float f32x4;

// fp32 -> bf16 (RNE) bit pattern
__device__ __forceinline__ short f2bf(float f) {
    union { float f; unsigned u; } v; v.f = f;
    unsigned r = v.u + 0x7fffu + ((v.u >> 16) & 1u);
    return (short)(r >> 16);
}

// ---------------------------------------------------------------- dist ------
__global__ __launch_bounds__(256) void dist_kernel(fp32p pos, float* __restrict__ dist) {
    const int i = blockIdx.x;
    const float xi = pos[2 * i];
    const float yi = pos[2 * i + 1];
    for (int j = threadIdx.x; j < NA; j += 256) {
        float dx = xi - pos[2 * j];
        float dy = yi - pos[2 * j + 1];
        float s = dx * dx + dy * dy;
        dist[i * NA + j] = (i == j) ? 0.0f : sqrtf(s);
    }
}

// ------------------------------------------------------------- encoder ------
__global__ __launch_bounds__(128) void encoder_kernel(
    fp32p obs, fp32p W1, fp32p b1, fp32p W2, fp32p b2, fp32p W3, fp32p b3,
    float* __restrict__ z) {
    __shared__ float xs[NOBS];
    __shared__ float h1s[NH];
    __shared__ float h2s[NH];
    const int i = blockIdx.x, t = threadIdx.x;
    if (t < NOBS) xs[t] = obs[i * NOBS + t];
    __syncthreads();
    float a = b1[t];
    for (int k = 0; k < NOBS; ++k) a += xs[k] * W1[t * NOBS + k];
    h1s[t] = fmaxf(a, 0.0f);
    __syncthreads();
    a = b2[t];
    for (int k = 0; k < NH; ++k) a += h1s[k] * W2[t * NH + k];
    h2s[t] = fmaxf(a, 0.0f);
    __syncthreads();
    a = b3[t];
    for (int k = 0; k < NH; ++k) a += h2s[k] * W3[t * NH + k];
    z[i * NH + t] = a;
}

// ------------------------------------------------- A = z@Wi.T, B = z@Wj.T ---
__global__ __launch_bounds__(128) void ab_kernel(
    const float* __restrict__ z, fp32p W1l, float* __restrict__ A, float* __restrict__ B) {
    __shared__ float zs[NH];
    const int i = blockIdx.x, m = threadIdx.x;
    zs[m] = z[i * NH + m];
    __syncthreads();
    const float* wr = W1l + m * 257;
    float a = 0.0f, b = 0.0f;
    for (int k = 0; k < NH; ++k) {
        float zk = zs[k];
        a += zk * wr[k];
        b += zk * wr[NH + k];
    }
    A[i * NH + m] = a;
    B[i * NH + m] = b;
}

// ------------------------------------------------------- fused message ------
// One block per target agent i; 8 waves. MFMA bf16 for the two pair-GEMMs.
// Wave w owns output cols n in [16w, 16w+16) for BOTH GEMMs -> W2/W3
// B-fragments (4 x bf16x8 each) are register-resident, loaded from global
// once. h1/h2 live in LDS as bf16, row stride 136 (=8*17: 16B aligned pad;
// b128 fragment reads spread evenly over banks, 8 lanes/4-bank-span = b128
// minimum). LDS ~38 KB -> 4 blocks/CU.
#define HSTR 136
__global__ __launch_bounds__(512) void msg_kernel(
    const float* __restrict__ A, const float* __restrict__ B,
    const float* __restrict__ dist,
    fp32p W1l, fp32p b1, fp32p W2, fp32p b2, fp32p W3, fp32p b3,
    float* __restrict__ msum) {
    const int i = blockIdx.x;
    const int t = threadIdx.x;
    const int lane = t & 63;
    const int w = t >> 6;         // wave 0..7
    const int q = lane >> 4;      // quad 0..3
    const int c = lane & 15;
    const int ncol = w * 16 + c;  // this lane's output column (both GEMMs)

    __shared__ short h1s[64 * HSTR];   // 17408 B
    __shared__ short h2s[64 * HSTR];   // 17408 B
    __shared__ float distrow[NA];      // 2048 B
    __shared__ float amrow[NH];        // A_i + b1 folded
    __shared__ float wdsr[NH];

    if (t < NH) {
        amrow[t] = A[i * NH + t] + b1[t];
        wdsr[t]  = W1l[t * 257 + 256];
    }
    if (t < NA) distrow[t] = dist[i * NA + t];

    // ---- register-resident weight fragments (B-operand layout:
    //      lane c -> row n=ncol of W, k = q*8 + kb*32 + j) ----
    bf16x8 w2f[4], w3f[4];
    {
        const float* w2r = W2 + (size_t)ncol * NH + q * 8;
        const float* w3r = W3 + (size_t)ncol * NH + q * 8;
        #pragma unroll
        for (int kb = 0; kb < 4; ++kb) {
            #pragma unroll
            for (int j = 0; j < 8; ++j) {
                w2f[kb][j] = f2bf(w2r[kb * 32 + j]);
                w3f[kb][j] = f2bf(w3r[kb * 32 + j]);
            }
        }
    }
    const float b2n = b2[ncol];
    const float b3n = b3[ncol];

    // h1-build lane constants: cols m2, m2+1; rows {w, 8+w, .., 56+w}
    const int m2 = lane * 2;
    float psum = 0.0f;

    for (int c8 = 0; c8 < 8; ++c8) {
        const int j0 = c8 * 64;
        __syncthreads();  // h1s consumed by prev GEMM1, h2s by prev GEMM2; preload done

        // ---- build h1 chunk (64 x 128) as bf16 ----
        {
            const float am0 = amrow[m2],     am1 = amrow[m2 + 1];
            const float wd0 = wdsr[m2],      wd1 = wdsr[m2 + 1];
            #pragma unroll
            for (int rr = 0; rr < 8; ++rr) {
                const int row = rr * 8 + w;
                const int jg  = j0 + row;
                const float2 bv = *(const float2*)&B[(size_t)jg * NH + m2];
                const float d = distrow[jg];
                const float v0 = fmaxf(am0 + bv.x + d * wd0, 0.0f);
                const float v1 = fmaxf(am1 + bv.y + d * wd1, 0.0f);
                const unsigned p = (unsigned)(unsigned short)f2bf(v0) |
                                   ((unsigned)(unsigned short)f2bf(v1) << 16);
                *(unsigned*)&h1s[row * HSTR + m2] = p;
            }
        }
        __syncthreads();

        // ---- GEMM1: h2 = relu(h1 @ W2^T + b2), write bf16 to LDS ----
        #pragma unroll
        for (int jt = 0; jt < 4; ++jt) {
            f32x4 acc = {0.f, 0.f, 0.f, 0.f};
            const short* arow = &h1s[(jt * 16 + c) * HSTR + q * 8];
            #pragma unroll
            for (int kb = 0; kb < 4; ++kb) {
                bf16x8 a = *(const bf16x8*)(arow + kb * 32);
                acc = __builtin_amdgcn_mfma_f32_16x16x32_bf16(a, w2f[kb], acc, 0, 0, 0);
            }
            #pragma unroll
            for (int r = 0; r < 4; ++r) {
                const int row = jt * 16 + q * 4 + r;
                h2s[row * HSTR + ncol] = f2bf(fmaxf(acc[r] + b2n, 0.0f));
            }
        }
        __syncthreads();

        // ---- GEMM2: m = h2 @ W3^T + b3, diag-masked column sum ----
        #pragma unroll
        for (int jt = 0; jt < 4; ++jt) {
            f32x4 acc = {0.f, 0.f, 0.f, 0.f};
            const short* arow = &h2s[(jt * 16 + c) * HSTR + q * 8];
            #pragma unroll
            for (int kb = 0; kb < 4; ++kb) {
                bf16x8 a = *(const bf16x8*)(arow + kb * 32);
                acc = __builtin_amdgcn_mfma_f32_16x16x32_bf16(a, w3f[kb], acc, 0, 0, 0);
            }
            #pragma unroll
            for (int r = 0; r < 4; ++r) {
                const int jg = j0 + jt * 16 + q * 4 + r;
                if (jg != i) psum += acc[r] + b3n;
            }
        }
    }

    // ---- reduce psum over the 4 quads (same ncol) and store ----
    psum += __shfl_xor(psum, 16, 64);
    psum += __shfl_xor(psum, 32, 64);
    if (lane < 16) msum[i * NH + ncol] = psum;
}

// -------------------------------------------------------------- update ------
__global__ __launch_bounds__(128) void upd_kernel(
    const float* __restrict__ z, const float* __restrict__ msum,
    fp32p W1, fp32p b1, fp32p W2, fp32p b2, fp32p W3, fp32p b3,
    float* __restrict__ zout) {
    __shared__ float xs[2 * NH];
    __shared__ float h1s[NH];
    __shared__ float h2s[NH];
    const int i = blockIdx.x, t = threadIdx.x;
    xs[t]      = z[i * NH + t];
    xs[NH + t] = msum[i * NH + t];
    __syncthreads();
    float a = b1[t];
    for (int k = 0; k < 2 * NH; ++k) a += xs[k] * W1[t * 2 * NH + k];
    h1s[t] = fmaxf(a, 0.0f);
    __syncthreads();
    a = b2[t];
    for (int k = 0; k < NH; ++k) a += h1s[k] * W2[t * NH + k];
    h2s[t] = fmaxf(a, 0.0f);
    __syncthreads();
    a = b3[t];
    for (int k = 0; k < NH; ++k) a += h2s[k] * W3[t * NH + k];
    zout[i * NH + t] = a;
}

// ---------------------------------------------------------------- host ------
extern "C" void kernel_launch(void* const* d_in, const int* in_sizes, int n_in,
                              void* d_out, int out_size, void* d_ws, size_t ws_size,
                              hipStream_t stream) {
    fp32p obs   = (fp32p)d_in[0];
    fp32p pos   = (fp32p)d_in[1];
    fp32p encW1 = (fp32p)d_in[2];  fp32p encb1 = (fp32p)d_in[3];
    fp32p encW2 = (fp32p)d_in[4];  fp32p encb2 = (fp32p)d_in[5];
    fp32p encW3 = (fp32p)d_in[6];  fp32p encb3 = (fp32p)d_in[7];
    fp32p msgW1 = (fp32p)d_in[8];  fp32p msgb1 = (fp32p)d_in[9];
    fp32p msgW2 = (fp32p)d_in[10]; fp32p msgb2 = (fp32p)d_in[11];
    fp32p msgW3 = (fp32p)d_in[12]; fp32p msgb3 = (fp32p)d_in[13];
    fp32p updW1 = (fp32p)d_in[14]; fp32p updb1 = (fp32p)d_in[15];
    fp32p updW2 = (fp32p)d_in[16]; fp32p updb2 = (fp32p)d_in[17];
    fp32p updW3 = (fp32p)d_in[18]; fp32p updb3 = (fp32p)d_in[19];

    // workspace layout (fp32): dist 512x512 | zA | zB | A | B | msum  (~2.36 MB)
    float* ws   = (float*)d_ws;
    float* dist = ws;
    float* zA   = dist + NA * NA;
    float* zB   = zA + NA * NH;
    float* Ab   = zB + NA * NH;
    float* Bb   = Ab + NA * NH;
    float* ms   = Bb + NA * NH;

    dist_kernel<<<NA, 256, 0, stream>>>(pos, dist);
    encoder_kernel<<<NA, 128, 0, stream>>>(obs, encW1, encb1, encW2, encb2, encW3, encb3, zA);

    float* zin = zA;
    float* zout = zB;
    for (int l = 0; l < 3; ++l) {
        ab_kernel<<<NA, 128, 0, stream>>>(zin, msgW1 + (size_t)l * 128 * 257, Ab, Bb);
        msg_kernel<<<NA, 512, 0, stream>>>(Ab, Bb, dist,
            msgW1 + (size_t)l * 128 * 257, msgb1 + l * 128,
            msgW2 + (size_t)l * 128 * 128, msgb2 + l * 128,
            msgW3 + (size_t)l * 128 * 128, msgb3 + l * 128, ms);
        float* dst = (l == 2) ? (float*)d_out : zout;
        upd_kernel<<<NA, 128, 0, stream>>>(zin, ms,
            updW1 + (size_t)l * 256 * 128, updb1 + l * 128,
            updW2 + (size_t)l * 128 * 128, updb2 + l * 128,
            updW3 + (size_t)l * 128 * 128, updb3 + l * 128, dst);
        float* tmp = zin; zin = zout; zout = tmp;
    }
}

// Round 4
// 255.995 us; speedup vs baseline: 4.3160x; 1.1360x over previous
//
#include <hip/hip_runtime.h>

// Problem constants (from reference): N=512, OBS=32, H=128, M=128, L=3
#define NA 512
#define NOBS 32
#define NH 128

typedef const float* fp32p;
typedef __attribute__((ext_vector_type(8))) short bf16x8;
typedef __attribute__((ext_vector_type(4))) float f32x4;

// fp32 -> bf16 (RNE) bit pattern
__device__ __forceinline__ short f2bf(float f) {
    union { float f; unsigned u; } v; v.f = f;
    unsigned r = v.u + 0x7fffu + ((v.u >> 16) & 1u);
    return (short)(r >> 16);
}

// weight fragment loads: 8 consecutive floats -> bf16x8 (B-operand layout:
// lane c -> weight row ncol, k = kb*32 + q*8 + j). Same operand convention
// verified by the passing round-3 msg_kernel.
__device__ __forceinline__ bf16x8 wfrag_f4(const float* p) {  // 16B-aligned
    float4 u = *(const float4*)p;
    float4 v = *(const float4*)(p + 4);
    bf16x8 f;
    f[0] = f2bf(u.x); f[1] = f2bf(u.y); f[2] = f2bf(u.z); f[3] = f2bf(u.w);
    f[4] = f2bf(v.x); f[5] = f2bf(v.y); f[6] = f2bf(v.z); f[7] = f2bf(v.w);
    return f;
}
__device__ __forceinline__ bf16x8 wfrag_s(const float* p) {   // unaligned ok
    bf16x8 f;
    #pragma unroll
    for (int j = 0; j < 8; ++j) f[j] = f2bf(p[j]);
    return f;
}

#define HSTR 136   // LDS row stride (shorts) for 128-wide bf16 tiles
#define XSTR 40    // for 32-wide obs tile
#define USTR 264   // for 256-wide upd input tile

// ------------------------------------------------ encoder + ab(layer0) -----
// grid 8 x 512. Block handles 64 agents through enc L1..L3 (MFMA), then
// A = z@Wi^T, B = z@Wj^T for msg layer 0.
__global__ __launch_bounds__(512) void enc_ab_kernel(
    fp32p obs, fp32p W1, fp32p b1, fp32p W2, fp32p b2, fp32p W3, fp32p b3,
    fp32p msgW1, float* __restrict__ z, float* __restrict__ A, float* __restrict__ B) {
    const int a0 = blockIdx.x * 64;
    const int t = threadIdx.x;
    const int lane = t & 63, w = t >> 6, q = lane >> 4, c = lane & 15;
    const int ncol = w * 16 + c;

    __shared__ short xs[64 * XSTR];    // obs tile
    __shared__ short h1s[64 * HSTR];   // also reused as z (bf16) for ab
    __shared__ short h2s[64 * HSTR];

    for (int e = t; e < 64 * NOBS; e += 512) {
        int r = e >> 5, k = e & 31;
        xs[r * XSTR + k] = f2bf(obs[(size_t)(a0 + r) * NOBS + k]);
    }
    // L1 (K=32): one MFMA per row-tile
    bf16x8 wf = wfrag_f4(W1 + (size_t)ncol * NOBS + q * 8);
    const float bias1 = b1[ncol];
    __syncthreads();
    #pragma unroll
    for (int jt = 0; jt < 4; ++jt) {
        f32x4 acc = {0.f, 0.f, 0.f, 0.f};
        bf16x8 a = *(const bf16x8*)&xs[(jt * 16 + c) * XSTR + q * 8];
        acc = __builtin_amdgcn_mfma_f32_16x16x32_bf16(a, wf, acc, 0, 0, 0);
        #pragma unroll
        for (int r = 0; r < 4; ++r)
            h1s[(jt * 16 + q * 4 + r) * HSTR + ncol] = f2bf(fmaxf(acc[r] + bias1, 0.f));
    }
    // L2 (K=128)
    bf16x8 w2f[4];
    #pragma unroll
    for (int kb = 0; kb < 4; ++kb) w2f[kb] = wfrag_f4(W2 + (size_t)ncol * NH + kb * 32 + q * 8);
    const float bias2 = b2[ncol];
    __syncthreads();
    #pragma unroll
    for (int jt = 0; jt < 4; ++jt) {
        f32x4 acc = {0.f, 0.f, 0.f, 0.f};
        #pragma unroll
        for (int kb = 0; kb < 4; ++kb) {
            bf16x8 a = *(const bf16x8*)&h1s[(jt * 16 + c) * HSTR + kb * 32 + q * 8];
            acc = __builtin_amdgcn_mfma_f32_16x16x32_bf16(a, w2f[kb], acc, 0, 0, 0);
        }
        #pragma unroll
        for (int r = 0; r < 4; ++r)
            h2s[(jt * 16 + q * 4 + r) * HSTR + ncol] = f2bf(fmaxf(acc[r] + bias2, 0.f));
    }
    // L3 (K=128, no relu) -> z global fp32 + bf16 into h1s (reuse as zs)
    bf16x8 w3f[4];
    #pragma unroll
    for (int kb = 0; kb < 4; ++kb) w3f[kb] = wfrag_f4(W3 + (size_t)ncol * NH + kb * 32 + q * 8);
    const float bias3 = b3[ncol];
    __syncthreads();
    #pragma unroll
    for (int jt = 0; jt < 4; ++jt) {
        f32x4 acc = {0.f, 0.f, 0.f, 0.f};
        #pragma unroll
        for (int kb = 0; kb < 4; ++kb) {
            bf16x8 a = *(const bf16x8*)&h2s[(jt * 16 + c) * HSTR + kb * 32 + q * 8];
            acc = __builtin_amdgcn_mfma_f32_16x16x32_bf16(a, w3f[kb], acc, 0, 0, 0);
        }
        #pragma unroll
        for (int r = 0; r < 4; ++r) {
            const int row = jt * 16 + q * 4 + r;
            const float v = acc[r] + bias3;
            z[(size_t)(a0 + row) * NH + ncol] = v;
            h1s[row * HSTR + ncol] = f2bf(v);
        }
    }
    // ab: A and B (K=128) from zs(=h1s); msg_W1 rows stride 257 (scalar frag)
    bf16x8 wif[4], wjf[4];
    #pragma unroll
    for (int kb = 0; kb < 4; ++kb) {
        const float* pr = msgW1 + (size_t)ncol * 257 + kb * 32 + q * 8;
        wif[kb] = wfrag_s(pr);
        wjf[kb] = wfrag_s(pr + NH);
    }
    __syncthreads();
    #pragma unroll
    for (int jt = 0; jt < 4; ++jt) {
        f32x4 accA = {0.f, 0.f, 0.f, 0.f};
        f32x4 accB = {0.f, 0.f, 0.f, 0.f};
        #pragma unroll
        for (int kb = 0; kb < 4; ++kb) {
            bf16x8 a = *(const bf16x8*)&h1s[(jt * 16 + c) * HSTR + kb * 32 + q * 8];
            accA = __builtin_amdgcn_mfma_f32_16x16x32_bf16(a, wif[kb], accA, 0, 0, 0);
            accB = __builtin_amdgcn_mfma_f32_16x16x32_bf16(a, wjf[kb], accB, 0, 0, 0);
        }
        #pragma unroll
        for (int r = 0; r < 4; ++r) {
            const int row = jt * 16 + q * 4 + r;
            A[(size_t)(a0 + row) * NH + ncol] = accA[r];
            B[(size_t)(a0 + row) * NH + ncol] = accB[r];
        }
    }
}

// ------------------------------------------------------- fused message ------
// One block per target agent i; 8 waves; dist row computed inline from pos.
__global__ __launch_bounds__(512) void msg_kernel(
    const float* __restrict__ A, const float* __restrict__ B,
    fp32p pos,
    fp32p W1l, fp32p b1, fp32p W2, fp32p b2, fp32p W3, fp32p b3,
    float* __restrict__ msum) {
    const int i = blockIdx.x;
    const int t = threadIdx.x;
    const int lane = t & 63;
    const int w = t >> 6;
    const int q = lane >> 4;
    const int c = lane & 15;
    const int ncol = w * 16 + c;

    __shared__ short h1s[64 * HSTR];   // 17408 B
    __shared__ short h2s[64 * HSTR];   // 17408 B
    __shared__ float distrow[NA];
    __shared__ float amrow[NH];        // A_i + b1 folded
    __shared__ float wdsr[NH];

    if (t < NH) {
        amrow[t] = A[i * NH + t] + b1[t];
        wdsr[t]  = W1l[t * 257 + 256];
    }
    {
        const float2 pi = *(const float2*)&pos[2 * i];
        const float2 pj = *(const float2*)&pos[2 * t];
        const float dx = pi.x - pj.x, dy = pi.y - pj.y;
        const float s = dx * dx + dy * dy;
        distrow[t] = (t == i) ? 0.0f : sqrtf(s);
    }

    bf16x8 w2f[4], w3f[4];
    {
        const float* w2r = W2 + (size_t)ncol * NH + q * 8;
        const float* w3r = W3 + (size_t)ncol * NH + q * 8;
        #pragma unroll
        for (int kb = 0; kb < 4; ++kb) {
            w2f[kb] = wfrag_f4(w2r + kb * 32);
            w3f[kb] = wfrag_f4(w3r + kb * 32);
        }
    }
    const float b2n = b2[ncol];
    const float b3n = b3[ncol];

    const int m2 = lane * 2;
    float psum = 0.0f;

    for (int c8 = 0; c8 < 8; ++c8) {
        const int j0 = c8 * 64;
        __syncthreads();  // prev chunk fully consumed; preload done

        // ---- build h1 chunk (64 x 128) as bf16 ----
        {
            const float am0 = amrow[m2],     am1 = amrow[m2 + 1];
            const float wd0 = wdsr[m2],      wd1 = wdsr[m2 + 1];
            #pragma unroll
            for (int rr = 0; rr < 8; ++rr) {
                const int row = rr * 8 + w;
                const int jg  = j0 + row;
                const float2 bv = *(const float2*)&B[(size_t)jg * NH + m2];
                const float d = distrow[jg];
                const float v0 = fmaxf(am0 + bv.x + d * wd0, 0.0f);
                const float v1 = fmaxf(am1 + bv.y + d * wd1, 0.0f);
                const unsigned p = (unsigned)(unsigned short)f2bf(v0) |
                                   ((unsigned)(unsigned short)f2bf(v1) << 16);
                *(unsigned*)&h1s[row * HSTR + m2] = p;
            }
        }
        __syncthreads();

        // ---- GEMM1: h2 = relu(h1 @ W2^T + b2) ----
        #pragma unroll
        for (int jt = 0; jt < 4; ++jt) {
            f32x4 acc = {0.f, 0.f, 0.f, 0.f};
            const short* arow = &h1s[(jt * 16 + c) * HSTR + q * 8];
            #pragma unroll
            for (int kb = 0; kb < 4; ++kb) {
                bf16x8 a = *(const bf16x8*)(arow + kb * 32);
                acc = __builtin_amdgcn_mfma_f32_16x16x32_bf16(a, w2f[kb], acc, 0, 0, 0);
            }
            #pragma unroll
            for (int r = 0; r < 4; ++r) {
                const int row = jt * 16 + q * 4 + r;
                h2s[row * HSTR + ncol] = f2bf(fmaxf(acc[r] + b2n, 0.0f));
            }
        }
        __syncthreads();

        // ---- GEMM2: diag-masked column sum of h2 @ W3^T + b3 ----
        #pragma unroll
        for (int jt = 0; jt < 4; ++jt) {
            f32x4 acc = {0.f, 0.f, 0.f, 0.f};
            const short* arow = &h2s[(jt * 16 + c) * HSTR + q * 8];
            #pragma unroll
            for (int kb = 0; kb < 4; ++kb) {
                bf16x8 a = *(const bf16x8*)(arow + kb * 32);
                acc = __builtin_amdgcn_mfma_f32_16x16x32_bf16(a, w3f[kb], acc, 0, 0, 0);
            }
            #pragma unroll
            for (int r = 0; r < 4; ++r) {
                const int jg = j0 + jt * 16 + q * 4 + r;
                if (jg != i) psum += acc[r] + b3n;
            }
        }
    }

    psum += __shfl_xor(psum, 16, 64);
    psum += __shfl_xor(psum, 32, 64);
    if (lane < 16) msum[i * NH + ncol] = psum;
}

// ------------------------------------------- update + ab(next layer) --------
// grid 8 x 512. x = [z | msum] (64 x 256) -> 3 MFMA layers -> zout;
// optionally A,B for the next msg layer.
__global__ __launch_bounds__(512) void upd_ab_kernel(
    fp32p zin, fp32p ms,
    fp32p W1, fp32p b1, fp32p W2, fp32p b2, fp32p W3, fp32p b3,
    fp32p msgW1n, int do_ab,
    float* __restrict__ zout, float* __restrict__ A, float* __restrict__ B) {
    const int a0 = blockIdx.x * 64;
    const int t = threadIdx.x;
    const int lane = t & 63, w = t >> 6, q = lane >> 4, c = lane & 15;
    const int ncol = w * 16 + c;

    __shared__ short xs[64 * USTR];    // 33792 B
    __shared__ short h1s[64 * HSTR];   // reused as z (bf16) for ab
    __shared__ short h2s[64 * HSTR];

    for (int e = t; e < 64 * 256; e += 512) {
        int r = e >> 8, k = e & 255;
        float v = (k < NH) ? zin[(size_t)(a0 + r) * NH + k]
                           : ms[(size_t)(a0 + r) * NH + (k - NH)];
        xs[r * USTR + k] = f2bf(v);
    }
    // L1 (K=256)
    bf16x8 w1f[8];
    #pragma unroll
    for (int kb = 0; kb < 8; ++kb) w1f[kb] = wfrag_f4(W1 + (size_t)ncol * 256 + kb * 32 + q * 8);
    const float bias1 = b1[ncol];
    __syncthreads();
    #pragma unroll
    for (int jt = 0; jt < 4; ++jt) {
        f32x4 acc = {0.f, 0.f, 0.f, 0.f};
        #pragma unroll
        for (int kb = 0; kb < 8; ++kb) {
            bf16x8 a = *(const bf16x8*)&xs[(jt * 16 + c) * USTR + kb * 32 + q * 8];
            acc = __builtin_amdgcn_mfma_f32_16x16x32_bf16(a, w1f[kb], acc, 0, 0, 0);
        }
        #pragma unroll
        for (int r = 0; r < 4; ++r)
            h1s[(jt * 16 + q * 4 + r) * HSTR + ncol] = f2bf(fmaxf(acc[r] + bias1, 0.f));
    }
    // L2 (K=128)
    bf16x8 w2f[4];
    #pragma unroll
    for (int kb = 0; kb < 4; ++kb) w2f[kb] = wfrag_f4(W2 + (size_t)ncol * NH + kb * 32 + q * 8);
    const float bias2 = b2[ncol];
    __syncthreads();
    #pragma unroll
    for (int jt = 0; jt < 4; ++jt) {
        f32x4 acc = {0.f, 0.f, 0.f, 0.f};
        #pragma unroll
        for (int kb = 0; kb < 4; ++kb) {
            bf16x8 a = *(const bf16x8*)&h1s[(jt * 16 + c) * HSTR + kb * 32 + q * 8];
            acc = __builtin_amdgcn_mfma_f32_16x16x32_bf16(a, w2f[kb], acc, 0, 0, 0);
        }
        #pragma unroll
        for (int r = 0; r < 4; ++r)
            h2s[(jt * 16 + q * 4 + r) * HSTR + ncol] = f2bf(fmaxf(acc[r] + bias2, 0.f));
    }
    // L3 (K=128, no relu) -> zout fp32 (+ bf16 zs if ab follows)
    bf16x8 w3f[4];
    #pragma unroll
    for (int kb = 0; kb < 4; ++kb) w3f[kb] = wfrag_f4(W3 + (size_t)ncol * NH + kb * 32 + q * 8);
    const float bias3 = b3[ncol];
    __syncthreads();
    #pragma unroll
    for (int jt = 0; jt < 4; ++jt) {
        f32x4 acc = {0.f, 0.f, 0.f, 0.f};
        #pragma unroll
        for (int kb = 0; kb < 4; ++kb) {
            bf16x8 a = *(const bf16x8*)&h2s[(jt * 16 + c) * HSTR + kb * 32 + q * 8];
            acc = __builtin_amdgcn_mfma_f32_16x16x32_bf16(a, w3f[kb], acc, 0, 0, 0);
        }
        #pragma unroll
        for (int r = 0; r < 4; ++r) {
            const int row = jt * 16 + q * 4 + r;
            const float v = acc[r] + bias3;
            zout[(size_t)(a0 + row) * NH + ncol] = v;
            if (do_ab) h1s[row * HSTR + ncol] = f2bf(v);
        }
    }
    if (!do_ab) return;
    // ab for next msg layer
    bf16x8 wif[4], wjf[4];
    #pragma unroll
    for (int kb = 0; kb < 4; ++kb) {
        const float* pr = msgW1n + (size_t)ncol * 257 + kb * 32 + q * 8;
        wif[kb] = wfrag_s(pr);
        wjf[kb] = wfrag_s(pr + NH);
    }
    __syncthreads();
    #pragma unroll
    for (int jt = 0; jt < 4; ++jt) {
        f32x4 accA = {0.f, 0.f, 0.f, 0.f};
        f32x4 accB = {0.f, 0.f, 0.f, 0.f};
        #pragma unroll
        for (int kb = 0; kb < 4; ++kb) {
            bf16x8 a = *(const bf16x8*)&h1s[(jt * 16 + c) * HSTR + kb * 32 + q * 8];
            accA = __builtin_amdgcn_mfma_f32_16x16x32_bf16(a, wif[kb], accA, 0, 0, 0);
            accB = __builtin_amdgcn_mfma_f32_16x16x32_bf16(a, wjf[kb], accB, 0, 0, 0);
        }
        #pragma unroll
        for (int r = 0; r < 4; ++r) {
            const int row = jt * 16 + q * 4 + r;
            A[(size_t)(a0 + row) * NH + ncol] = accA[r];
            B[(size_t)(a0 + row) * NH + ncol] = accB[r];
        }
    }
}

// ---------------------------------------------------------------- host ------
extern "C" void kernel_launch(void* const* d_in, const int* in_sizes, int n_in,
                              void* d_out, int out_size, void* d_ws, size_t ws_size,
                              hipStream_t stream) {
    fp32p obs   = (fp32p)d_in[0];
    fp32p pos   = (fp32p)d_in[1];
    fp32p encW1 = (fp32p)d_in[2];  fp32p encb1 = (fp32p)d_in[3];
    fp32p encW2 = (fp32p)d_in[4];  fp32p encb2 = (fp32p)d_in[5];
    fp32p encW3 = (fp32p)d_in[6];  fp32p encb3 = (fp32p)d_in[7];
    fp32p msgW1 = (fp32p)d_in[8];  fp32p msgb1 = (fp32p)d_in[9];
    fp32p msgW2 = (fp32p)d_in[10]; fp32p msgb2 = (fp32p)d_in[11];
    fp32p msgW3 = (fp32p)d_in[12]; fp32p msgb3 = (fp32p)d_in[13];
    fp32p updW1 = (fp32p)d_in[14]; fp32p updb1 = (fp32p)d_in[15];
    fp32p updW2 = (fp32p)d_in[16]; fp32p updb2 = (fp32p)d_in[17];
    fp32p updW3 = (fp32p)d_in[18]; fp32p updb3 = (fp32p)d_in[19];

    // workspace (fp32): zA | zB | A | B | msum   (~1.3 MB)
    float* ws = (float*)d_ws;
    float* zA = ws;
    float* zB = zA + NA * NH;
    float* Ab = zB + NA * NH;
    float* Bb = Ab + NA * NH;
    float* ms = Bb + NA * NH;

    enc_ab_kernel<<<8, 512, 0, stream>>>(obs, encW1, encb1, encW2, encb2,
                                         encW3, encb3, msgW1, zA, Ab, Bb);

    float* zin = zA;
    float* zout = zB;
    for (int l = 0; l < 3; ++l) {
        msg_kernel<<<NA, 512, 0, stream>>>(Ab, Bb, pos,
            msgW1 + (size_t)l * 128 * 257, msgb1 + l * 128,
            msgW2 + (size_t)l * 128 * 128, msgb2 + l * 128,
            msgW3 + (size_t)l * 128 * 128, msgb3 + l * 128, ms);
        const int do_ab = (l < 2);
        float* dst = (l == 2) ? (float*)d_out : zout;
        upd_ab_kernel<<<8, 512, 0, stream>>>(zin, ms,
            updW1 + (size_t)l * 256 * 128, updb1 + l * 128,
            updW2 + (size_t)l * 128 * 128, updb2 + l * 128,
            updW3 + (size_t)l * 128 * 128, updb3 + l * 128,
            msgW1 + (size_t)(l + 1) * 128 * 257, do_ab, dst, Ab, Bb);
        float* tmp = zin; zin = zout; zout = tmp;
    }
}